// Round 1
// baseline (1725.855 us; speedup 1.0000x reference)
//
#include <hip/hip_runtime.h>
#include <hip/hip_bf16.h>

// Problem constants
#define B_ 32
#define T_ 600
#define CIN_ 1024
#define CBLK_ 128
#define W_ 16
#define NIN_ 7
#define NOUT_ 7

// ---------------------------------------------------------------------------
// zero scratch accumulators
__global__ void zero_kernel(float* __restrict__ p, int n) {
    int i = blockIdx.x * 256 + threadIdx.x;
    if (i < n) p[i] = 0.f;
}

// ---------------------------------------------------------------------------
// Fused 1x1-conv GEMM: out[b,o,t] = bn(relu(sum_c W[o,c]*in[b,c,t] + bias[o]))
// in = in0 (+ in1 if HAS_IN2). Optional per-(b,o) time-sum accumulation (SE).
template<bool HAS_IN2, bool DO_SSUM>
__global__ __launch_bounds__(256) void gemm_kernel(
    const float* __restrict__ in0, int s0,     // b-stride of in0
    const float* __restrict__ in1,             // b-stride 614400 (x slice)
    const float* __restrict__ Wg, const float* __restrict__ bias,
    const float* __restrict__ bnp, float* __restrict__ out,
    float* __restrict__ ssum)
{
    __shared__ float aT[128][64];
    __shared__ float wT[32][132];
    const int tid = threadIdx.x;
    const int b = blockIdx.y;
    const int t0 = blockIdx.x * 64;

    // stage input tile (zero beyond T)
    for (int e = tid; e < 128 * 64; e += 256) {
        int c = e >> 6, t = e & 63, g = t0 + t;
        float v = 0.f;
        if (g < T_) {
            v = in0[b * s0 + c * T_ + g];
            if (HAS_IN2) v += in1[b * 614400 + c * T_ + g];
        }
        aT[c][t] = v;
    }

    float acc[4][8];
#pragma unroll
    for (int q = 0; q < 4; ++q)
#pragma unroll
        for (int d = 0; d < 8; ++d) acc[q][d] = 0.f;

    const int og = tid >> 3, tg = tid & 7;
    const int o0 = og * 4, tt0 = tg * 8;

    for (int kb = 0; kb < 4; ++kb) {
        __syncthreads();   // aT ready (kb=0) / previous wT use done
        for (int e = tid; e < 32 * 128; e += 256) {
            int o = e >> 5, kk = e & 31;
            wT[kk][o] = Wg[o * 128 + kb * 32 + kk];
        }
        __syncthreads();
#pragma unroll
        for (int kk = 0; kk < 32; ++kk) {
            float4 w4 = *(const float4*)&wT[kk][o0];
            float4 x0 = *(const float4*)&aT[kb * 32 + kk][tt0];
            float4 x1 = *(const float4*)&aT[kb * 32 + kk][tt0 + 4];
            acc[0][0] += w4.x * x0.x; acc[0][1] += w4.x * x0.y;
            acc[0][2] += w4.x * x0.z; acc[0][3] += w4.x * x0.w;
            acc[0][4] += w4.x * x1.x; acc[0][5] += w4.x * x1.y;
            acc[0][6] += w4.x * x1.z; acc[0][7] += w4.x * x1.w;
            acc[1][0] += w4.y * x0.x; acc[1][1] += w4.y * x0.y;
            acc[1][2] += w4.y * x0.z; acc[1][3] += w4.y * x0.w;
            acc[1][4] += w4.y * x1.x; acc[1][5] += w4.y * x1.y;
            acc[1][6] += w4.y * x1.z; acc[1][7] += w4.y * x1.w;
            acc[2][0] += w4.z * x0.x; acc[2][1] += w4.z * x0.y;
            acc[2][2] += w4.z * x0.z; acc[2][3] += w4.z * x0.w;
            acc[2][4] += w4.z * x1.x; acc[2][5] += w4.z * x1.y;
            acc[2][6] += w4.z * x1.z; acc[2][7] += w4.z * x1.w;
            acc[3][0] += w4.w * x0.x; acc[3][1] += w4.w * x0.y;
            acc[3][2] += w4.w * x0.z; acc[3][3] += w4.w * x0.w;
            acc[3][4] += w4.w * x1.x; acc[3][5] += w4.w * x1.y;
            acc[3][6] += w4.w * x1.z; acc[3][7] += w4.w * x1.w;
        }
    }

    // epilogue: bias -> relu -> bn -> store (+ optional SE partial sum)
#pragma unroll
    for (int q = 0; q < 4; ++q) {
        int o = o0 + q;
        float g = bnp[o], bb = bnp[128 + o], m = bnp[256 + o], vv = bnp[384 + o];
        float sc = g * rsqrtf(vv + 1e-5f);
        float sh = bb - m * sc;
        float bs = bias[o];
        float psum = 0.f;
#pragma unroll
        for (int d = 0; d < 8; ++d) {
            int gt = t0 + tt0 + d;
            float v = fmaxf(acc[q][d] + bs, 0.f) * sc + sh;
            if (gt < T_) {
                out[(b * 128 + o) * T_ + gt] = v;
                psum += v;
            }
        }
        if (DO_SSUM) {
            psum += __shfl_xor(psum, 1);
            psum += __shfl_xor(psum, 2);
            psum += __shfl_xor(psum, 4);
            if (tg == 0) atomicAdd(&ssum[b * 128 + o], psum);
        }
    }
}

// ---------------------------------------------------------------------------
// Fused inner Res2 chain: 7 dependent dilated convs, entirely in LDS.
// t-tile 48, halo 14 each side. LDS state double-buffered [2][8][16][78].
constexpr int ITT = 48;      // central columns per workgroup
constexpr int ITB = 76;      // buffer extent = ITT + 28
constexpr int ITBP = 78;     // padded row length

__global__ __launch_bounds__(256) void inner_kernel(
    const float* __restrict__ out1, float* __restrict__ mid,
    const float* __restrict__ cwB, const float* __restrict__ cbB,
    const float* __restrict__ ibnB,
    const float* __restrict__ ws0, const float* __restrict__ ws1,
    const float* __restrict__ ws2, const float* __restrict__ ws3,
    const float* __restrict__ ws4, const float* __restrict__ ws5,
    const float* __restrict__ ws6)
{
    __shared__ float st[16][16][ITBP];   // [slot][ch][t]; slots 0-7 / 8-15 ping-pong
    __shared__ float wsL[35];
    __shared__ float cbL[112], iscL[112], ishL[112];

    const int tid = threadIdx.x;
    const int b = blockIdx.y, tile = blockIdx.x;
    const int t0g = tile * ITT - 14;

    // stage small per-branch params
    if (tid < 112) {
        int j = tid >> 4, c = tid & 15;
        float g = ibnB[(j * 4 + 0) * 16 + c], bb = ibnB[(j * 4 + 1) * 16 + c];
        float m = ibnB[(j * 4 + 2) * 16 + c], v = ibnB[(j * 4 + 3) * 16 + c];
        float sc = g * rsqrtf(v + 1e-5f);
        iscL[tid] = sc; ishL[tid] = bb - m * sc;
        cbL[tid] = cbB[tid];
    }
    if (tid >= 128 && tid < 163) {
        int idx = tid - 128;  // 0..34 ; off(j) = j*(j+3)/2
        int j = 0;
        while (j < 6 && (j + 1) * (j + 4) / 2 <= idx) ++j;
        int s = idx - j * (j + 3) / 2;
        const float* p;
        switch (j) {
            case 0: p = ws0; break; case 1: p = ws1; break; case 2: p = ws2; break;
            case 3: p = ws3; break; case 4: p = ws4; break; case 5: p = ws5; break;
            default: p = ws6; break;
        }
        wsL[idx] = p[s];
    }
    // initial slice 0 = out1 channels 112..127 over full buffer
    for (int e = tid; e < 16 * ITB; e += 256) {
        int i = e / ITB, t = e - i * ITB, g = t0g + t;
        st[0][i][t] = (g >= 0 && g < T_) ? out1[(b * 128 + 112 + i) * T_ + g] : 0.f;
    }
    __syncthreads();

    int cur = 0;
    for (int j = 0; j < 7; ++j) {
        const int ilo = 2 * j, ihi = ITB - 2 * j, ext = ihi - ilo;
        // load fresh slice j+1 (= out1 channels 16j..16j+15) into cur
        for (int e = tid; e < 16 * ext; e += 256) {
            int i = e / ext, t = ilo + (e - i * ext), g = t0g + t;
            st[cur * 8 + j + 1][i][t] =
                (g >= 0 && g < T_) ? out1[(b * 128 + 16 * j + i) * T_ + g] : 0.f;
        }
        // weighted-sum output of the PREVIOUS step (disjoint slices from load)
        if (j > 0) {
            int jj = j - 1, nsl = jj + 2, base = jj * (jj + 3) / 2;
            for (int e = tid; e < 16 * ITT; e += 256) {
                int o = e / ITT, tt = e - o * ITT;
                int t = 14 + tt, g = t0g + t;
                if (g < T_) {
                    float sum = 0.f;
                    for (int s = 0; s < nsl; ++s)
                        sum += st[cur * 8 + s][o][t] * wsL[base + s];
                    mid[(b * 128 + 16 * jj + o) * T_ + g] = sum;
                }
            }
        }
        __syncthreads();

        // conv step j: read cur slices 0..j+1, write nxt slices 0..j+1
        const int olo = ilo + 2, ohi = ihi - 2, olen = ohi - olo;
        const int nch = (olen + 7) >> 3;
        const int items = (j + 2) * nch;
        const int op = tid & 7, slot0 = tid >> 3;

        float wA[16][3], wB[16][3];
#pragma unroll
        for (int i2 = 0; i2 < 16; ++i2)
#pragma unroll
            for (int k = 0; k < 3; ++k) {
                wA[i2][k] = cwB[((j * 16 + op) * 16 + i2) * 3 + k];
                wB[i2][k] = cwB[((j * 16 + op + 8) * 16 + i2) * 3 + k];
            }
        const float biasA = cbL[j * 16 + op],     biasB = cbL[j * 16 + op + 8];
        const float iscA = iscL[j * 16 + op],     ishA = ishL[j * 16 + op];
        const float iscB = iscL[j * 16 + op + 8], ishB = ishL[j * 16 + op + 8];

        for (int it = slot0; it < items; it += 32) {
            int s = it / nch, ch = it - s * nch;
            int tb0 = olo + ch * 8;
            float accA[8], accB[8];
#pragma unroll
            for (int d = 0; d < 8; ++d) { accA[d] = biasA; accB[d] = biasB; }
#pragma unroll
            for (int i2 = 0; i2 < 16; ++i2) {
                const float* row = &st[cur * 8 + s][i2][0];
                float v[12];
#pragma unroll
                for (int m = 0; m < 6; ++m) {
                    float2 r = *(const float2*)&row[tb0 - 2 + 2 * m];
                    v[2 * m] = r.x; v[2 * m + 1] = r.y;
                }
#pragma unroll
                for (int d = 0; d < 8; ++d) {
                    accA[d] += wA[i2][0] * v[d] + wA[i2][1] * v[d + 2] + wA[i2][2] * v[d + 4];
                    accB[d] += wB[i2][0] * v[d] + wB[i2][1] * v[d + 2] + wB[i2][2] * v[d + 4];
                }
            }
            int nxt = cur ^ 1;
#pragma unroll
            for (int d = 0; d < 8; ++d) {
                int t = tb0 + d, g = t0g + t;
                if (t < ohi) {
                    bool ok = (g >= 0 && g < T_);
                    float va = ok ? fmaxf(accA[d], 0.f) * iscA + ishA : 0.f;
                    float vb = ok ? fmaxf(accB[d], 0.f) * iscB + ishB : 0.f;
                    st[nxt * 8 + s][op][t] = va;
                    st[nxt * 8 + s][op + 8][t] = vb;
                }
            }
        }
        __syncthreads();
        cur ^= 1;
    }

    // final weighted sum (step 6) + copy channels 112..127
    {
        int nsl = 8, base = 27;
        for (int e = tid; e < 16 * ITT; e += 256) {
            int o = e / ITT, tt = e - o * ITT;
            int t = 14 + tt, g = t0g + t;
            if (g < T_) {
                float sum = 0.f;
                for (int s = 0; s < nsl; ++s)
                    sum += st[cur * 8 + s][o][t] * wsL[base + s];
                mid[(b * 128 + 96 + o) * T_ + g] = sum;
            }
        }
        for (int e = tid; e < 16 * ITT; e += 256) {
            int o = e / ITT, tt = e - o * ITT, g = tile * ITT + tt;
            if (g < T_)
                mid[(b * 128 + 112 + o) * T_ + g] = out1[(b * 128 + 112 + o) * T_ + g];
        }
    }
}

// ---------------------------------------------------------------------------
// SE excitation: s2 = sigmoid(W2 relu(W1 (ssum/T) + b1) + b2)
__global__ __launch_bounds__(128) void se_kernel(
    const float* __restrict__ ssum, const float* __restrict__ w1se,
    const float* __restrict__ b1se, const float* __restrict__ w2se,
    const float* __restrict__ b2se, float* __restrict__ s2b)
{
    __shared__ float sL[128], hL[16];
    const int tid = threadIdx.x, b = blockIdx.x;
    sL[tid] = ssum[b * 128 + tid] * (1.f / 600.f);
    __syncthreads();
    if (tid < 16) {
        float a = b1se[tid];
        for (int c = 0; c < 128; ++c) a += w1se[tid * 128 + c] * sL[c];
        hL[tid] = fmaxf(a, 0.f);
    }
    __syncthreads();
    float a = b2se[tid];
#pragma unroll
    for (int q = 0; q < 16; ++q) a += w2se[tid * 16 + q] * hL[q];
    s2b[b * 128 + tid] = 1.f / (1.f + expf(-a));
}

// ---------------------------------------------------------------------------
// Elementwise tail of a block: y = out3*s2 + residual; sp = obn(relu(y));
// store sp; pooled[b, chOff+c] = mean_t relu(fbn(sp)).
template<bool HAS_R2>
__global__ __launch_bounds__(256) void fuse_kernel(
    const float* __restrict__ out3, const float* __restrict__ s2b,
    const float* __restrict__ res0, int r0s,
    const float* __restrict__ res1,
    const float* __restrict__ obnp, const float* __restrict__ fbnp, int chOff,
    float* __restrict__ spOut, float* __restrict__ pooled)
{
    const int tid = threadIdx.x;
    const int row = blockIdx.x * 4 + (tid >> 6);
    const int lane = tid & 63;
    const int b = row >> 7, c = row & 127;
    const float s2v = s2b[b * 128 + c];
    float g = obnp[c], bb = obnp[128 + c], m = obnp[256 + c], v = obnp[384 + c];
    float osc = g * rsqrtf(v + 1e-5f), osh = bb - m * osc;
    int fc = chOff + c;
    float fg = fbnp[fc], fb2 = fbnp[1024 + fc], fm = fbnp[2048 + fc], fv = fbnp[3072 + fc];
    float fsc = fg * rsqrtf(fv + 1e-5f), fsh = fb2 - fm * fsc;
    int base = (b * 128 + c) * T_;
    float psum = 0.f;
    for (int t = lane; t < T_; t += 64) {
        float o3 = out3[base + t];
        float r = res0[b * r0s + c * T_ + t];
        if (HAS_R2) r += res1[b * 614400 + c * T_ + t];
        float fin = o3 * s2v + r;
        float sp = fmaxf(fin, 0.f) * osc + osh;
        spOut[base + t] = sp;
        psum += fmaxf(sp * fsc + fsh, 0.f);
    }
    for (int mo = 32; mo > 0; mo >>= 1) psum += __shfl_xor(psum, mo);
    if (lane == 0) pooled[b * 1024 + fc] = psum * (1.f / 600.f);
}

// pooled tail for x channels 896..1023 (raw last x slice through fbn/relu/mean)
__global__ __launch_bounds__(256) void pooledx_kernel(
    const float* __restrict__ x, const float* __restrict__ fbnp,
    float* __restrict__ pooled)
{
    const int tid = threadIdx.x;
    const int row = blockIdx.x * 4 + (tid >> 6);
    const int lane = tid & 63;
    const int b = row >> 7, c = row & 127;
    int fc = 896 + c;
    float fg = fbnp[fc], fb2 = fbnp[1024 + fc], fm = fbnp[2048 + fc], fv = fbnp[3072 + fc];
    float fsc = fg * rsqrtf(fv + 1e-5f), fsh = fb2 - fm * fsc;
    int base = (b * 1024 + fc) * T_;
    float psum = 0.f;
    for (int t = lane; t < T_; t += 64)
        psum += fmaxf(x[base + t] * fsc + fsh, 0.f);
    for (int mo = 32; mo > 0; mo >>= 1) psum += __shfl_xor(psum, mo);
    if (lane == 0) pooled[b * 1024 + fc] = psum * (1.f / 600.f);
}

// final classifier: (B,1024) @ (1024,2)^T + bias
__global__ __launch_bounds__(256) void logits_kernel(
    const float* __restrict__ pooled, const float* __restrict__ fcw,
    const float* __restrict__ fcb, float* __restrict__ outp)
{
    __shared__ float red[256];
    const int tid = threadIdx.x;
    const int item = tid & 63, part = tid >> 6;
    const int b = item >> 1, cls = item & 1;
    float a = 0.f;
    for (int c = part * 256; c < part * 256 + 256; ++c)
        a += pooled[b * 1024 + c] * fcw[cls * 1024 + c];
    red[tid] = a;
    __syncthreads();
    if (tid < 64)
        outp[b * 2 + cls] = red[tid] + red[tid + 64] + red[tid + 128] + red[tid + 192] + fcb[cls];
}

// ---------------------------------------------------------------------------
extern "C" void kernel_launch(void* const* d_in, const int* in_sizes, int n_in,
                              void* d_out, int out_size, void* d_ws, size_t ws_size,
                              hipStream_t stream) {
    const float* x    = (const float*)d_in[0];
    const float* w1   = (const float*)d_in[1];
    const float* b1   = (const float*)d_in[2];
    const float* bn1  = (const float*)d_in[3];
    const float* cw   = (const float*)d_in[4];
    const float* cb   = (const float*)d_in[5];
    const float* ibn  = (const float*)d_in[6];
    const float* w3   = (const float*)d_in[7];
    const float* b3   = (const float*)d_in[8];
    const float* bn3  = (const float*)d_in[9];
    const float* se1w = (const float*)d_in[10];
    const float* se1b = (const float*)d_in[11];
    const float* se2w = (const float*)d_in[12];
    const float* se2b = (const float*)d_in[13];
    const float* obn  = (const float*)d_in[14];
    const float* fbn  = (const float*)d_in[15];
    const float* fcw  = (const float*)d_in[16];
    const float* fcb  = (const float*)d_in[17];
    const float* wsp[7] = {(const float*)d_in[18], (const float*)d_in[19],
                           (const float*)d_in[20], (const float*)d_in[21],
                           (const float*)d_in[22], (const float*)d_in[23],
                           (const float*)d_in[24]};

    float* ws = (float*)d_ws;
    const int NT = 128 * T_ * B_;          // 2,457,600 per (B,128,T) tensor
    float* out1   = ws;
    float* mid    = out1 + NT;
    float* out3   = mid + NT;
    float* spA    = out3 + NT;
    float* spB    = spA + NT;
    float* sbuf   = spB + NT;              // 7*4096
    float* s2b    = sbuf + 7 * 4096;       // 4096
    float* pooled = s2b + 4096;            // 32768

    zero_kernel<<<(7 * 4096 + 255) / 256, 256, 0, stream>>>(sbuf, 7 * 4096);
    pooledx_kernel<<<1024, 256, 0, stream>>>(x, fbn, pooled);

    dim3 gGrid(10, B_);   // ceil(600/64) x B
    dim3 iGrid(13, B_);   // ceil(600/48) x B

    float* spBufs[2] = {spA, spB};
    for (int i = 0; i < 7; ++i) {
        float* spOut = spBufs[i & 1];
        const float* spIn = spBufs[(i & 1) ^ 1];

        if (i == 0)
            gemm_kernel<false, false><<<gGrid, 256, 0, stream>>>(
                x, 614400, nullptr, w1, b1, bn1, out1, nullptr);
        else
            gemm_kernel<true, false><<<gGrid, 256, 0, stream>>>(
                spIn, 76800, x + i * 76800,
                w1 + i * 16384, b1 + i * 128, bn1 + i * 512, out1, nullptr);

        inner_kernel<<<iGrid, 256, 0, stream>>>(
            out1, mid, cw + i * 5376, cb + i * 112, ibn + i * 448,
            wsp[0] + 2 * i, wsp[1] + 3 * i, wsp[2] + 4 * i, wsp[3] + 5 * i,
            wsp[4] + 6 * i, wsp[5] + 7 * i, wsp[6] + 8 * i);

        gemm_kernel<false, true><<<gGrid, 256, 0, stream>>>(
            mid, 76800, nullptr,
            w3 + i * 16384, b3 + i * 128, bn3 + i * 512, out3, sbuf + i * 4096);

        se_kernel<<<B_, 128, 0, stream>>>(
            sbuf + i * 4096, se1w + i * 2048, se1b + i * 16,
            se2w + i * 2048, se2b + i * 128, s2b);

        if (i == 0)
            fuse_kernel<false><<<1024, 256, 0, stream>>>(
                out3, s2b, x, 614400, nullptr, obn, fbn, 0, spOut, pooled);
        else
            fuse_kernel<true><<<1024, 256, 0, stream>>>(
                out3, s2b, spIn, 76800, x + i * 76800,
                obn + i * 512, fbn, i * 128, spOut, pooled);
    }

    logits_kernel<<<1, 256, 0, stream>>>(pooled, fcw, fcb, (float*)d_out);
}